// Round 5
// baseline (430.839 us; speedup 1.0000x reference)
//
#include <hip/hip_runtime.h>
#include <math.h>

#define NTHREADS 256
typedef __attribute__((ext_vector_type(8))) short short8;
typedef __attribute__((ext_vector_type(4))) float f32x4;
typedef unsigned short ushort_t;

// ---- Kernel A LDS: two time-major activation buffers hT[row=t+4][ch],
// 212 rows x stride 40 bf16 (80 B, 16B-aligned rows). B-frag = 8 contiguous
// channels at one row = one ds_read_b128. 33,920 B -> 4 blocks/CU.
#define HA    0          // bufA: h1, then h3
#define HB    8480       // bufB: xn (ch 0..5, rest zero), then h2
#define HSTR  40
#define SMEM_HW 16960

// ws layout: 35 A-frags bf16 (512 hw each) at 0; F fp32 at byte 65536.
#define WSF_C1 0
#define WSF_C2 (10*512)
#define WSF_C3 (20*512)
#define WSF_C4 (30*512)
#define WS_F_BYTE_OFF 65536

__device__ __forceinline__ unsigned f2bf(float f) {
    unsigned u = __float_as_uint(f);
    return (u + 0x7FFFu + ((u >> 16) & 1u)) >> 16;
}

__device__ __forceinline__ float gelu_fast(float x) {
    float x2 = x * x;
    float u  = x * fmaf(0.044715f, x2, 1.0f);
    float e  = __builtin_amdgcn_exp2f(u * 2.3022082f);
    float r  = __builtin_amdgcn_rcpf(e + 1.0f);
    float th = fmaf(-2.0f, r, 1.0f);
    float hx = 0.5f * x;
    return fmaf(hx, th, hx);
}

__device__ __forceinline__ float gelu_exact(float v) {
    return 0.5f * v * (1.0f + erff(v * 0.70710678118654752f));
}

#define JROT(Spp, Sqq, Spq, Sxp, Sxq, Vp0, Vq0, Vp1, Vq1, Vp2, Vq2)          \
    if (fabsf(Spq) > 1e-18f) {                                               \
        float tau = (Sqq - Spp) / (2.0f * Spq);                              \
        float tj = copysignf(1.0f, tau) / (fabsf(tau) + sqrtf(1.0f + tau*tau)); \
        float cj = 1.0f / sqrtf(1.0f + tj*tj);                               \
        float sj = tj * cj;                                                  \
        Spp -= tj * Spq; Sqq += tj * Spq; Spq = 0.0f;                        \
        float tmp0 = Sxp; Sxp = cj*tmp0 - sj*Sxq; Sxq = sj*tmp0 + cj*Sxq;    \
        float tv;                                                            \
        tv = Vp0; Vp0 = cj*tv - sj*Vq0; Vq0 = sj*tv + cj*Vq0;                \
        tv = Vp1; Vp1 = cj*tv - sj*Vq1; Vq1 = sj*tv + cj*Vq1;                \
        tv = Vp2; Vp2 = cj*tv - sj*Vq2; Vq2 = sj*tv + cj*Vq2;                \
    }

// ---- prep: repack conv weights into MFMA A-frag lane order (bf16).
// A-layout: lane l holds A[m=l&15][k=(l>>4)*8+j]; frag = 512 hw.
__global__ void prep_kernel(const float* __restrict__ cw1,
                            const float* __restrict__ cw2,
                            const float* __restrict__ cw3,
                            const float* __restrict__ cw4,
                            ushort_t* __restrict__ ws)
{
    const int fid = blockIdx.x;              // 0..34
    const int l = threadIdx.x >> 3, j = threadIdx.x & 7;
    const int lo = l & 15, q = l >> 4;
    const int k = q * 8 + j;                 // 0..31
    float v = 0.0f;
    if (fid < 10) {                          // conv1: K=32, only i<6 real
        int tap = fid >> 1, Mt = fid & 1, c = Mt * 16 + lo;
        if (k < 6) v = cw1[(c * 6 + k) * 5 + tap];
    } else if (fid < 20) {                   // conv2
        int f = fid - 10, tap = f >> 1, Mt = f & 1, c = Mt * 16 + lo;
        v = cw2[(c * 32 + k) * 5 + tap];
    } else if (fid < 30) {                   // conv3
        int f = fid - 20, tap = f >> 1, Mt = f & 1, c = Mt * 16 + lo;
        v = cw3[(c * 32 + k) * 5 + tap];
    } else {                                 // conv4: row 0 only
        int tap = fid - 30;
        if (lo == 0) v = cw4[k * 5 + tap];
    }
    ws[fid * 512 + l * 8 + j] = (ushort_t)f2bf(v);
}

// ---- process 1 or 2 conv tiles (tile t0 and t0+4) interleaved for ILP ----
template<int DIL, bool TWO>
__device__ __forceinline__ void conv_tiles(
    const ushort_t* __restrict__ src, ushort_t* __restrict__ dst,
    const short8 A[5][2], f32x4 b0, f32x4 b1, int Lout,
    int lo16, int quad, int t0)
{
    f32x4 acc00 = b0, acc01 = b1, acc10 = b0, acc11 = b1;
    const int n0a = t0 * 16, n0b = (t0 + 4) * 16;
    #pragma unroll
    for (int t = 0; t < 5; t++) {
        int ra = n0a + lo16 + DIL * t; if (DIL == 3) ra = min(ra, 211);
        short8 Ba = *(const short8*)(src + ra * HSTR + quad * 8);
        acc00 = __builtin_amdgcn_mfma_f32_16x16x32_bf16(A[t][0], Ba, acc00, 0, 0, 0);
        acc01 = __builtin_amdgcn_mfma_f32_16x16x32_bf16(A[t][1], Ba, acc01, 0, 0, 0);
        if (TWO) {
            int rb = n0b + lo16 + DIL * t; if (DIL == 3) rb = min(rb, 211);
            short8 Bb = *(const short8*)(src + rb * HSTR + quad * 8);
            acc10 = __builtin_amdgcn_mfma_f32_16x16x32_bf16(A[t][0], Bb, acc10, 0, 0, 0);
            acc11 = __builtin_amdgcn_mfma_f32_16x16x32_bf16(A[t][1], Bb, acc11, 0, 0, 0);
        }
    }
    {
        const int n = n0a + lo16;
        unsigned p00 = 0, p01 = 0, p10 = 0, p11 = 0;
        if (n < Lout) {
            p00 = f2bf(gelu_fast(acc00[0])) | (f2bf(gelu_fast(acc00[1])) << 16);
            p01 = f2bf(gelu_fast(acc00[2])) | (f2bf(gelu_fast(acc00[3])) << 16);
            p10 = f2bf(gelu_fast(acc01[0])) | (f2bf(gelu_fast(acc01[1])) << 16);
            p11 = f2bf(gelu_fast(acc01[2])) | (f2bf(gelu_fast(acc01[3])) << 16);
        }
        ushort_t* row = dst + (4 + n) * HSTR;
        *(uint2*)(row + quad * 4)      = make_uint2(p00, p01);
        *(uint2*)(row + 16 + quad * 4) = make_uint2(p10, p11);
    }
    if (TWO) {
        const int n = n0b + lo16;
        unsigned p00 = 0, p01 = 0, p10 = 0, p11 = 0;
        if (n < Lout) {
            p00 = f2bf(gelu_fast(acc10[0])) | (f2bf(gelu_fast(acc10[1])) << 16);
            p01 = f2bf(gelu_fast(acc10[2])) | (f2bf(gelu_fast(acc10[3])) << 16);
            p10 = f2bf(gelu_fast(acc11[0])) | (f2bf(gelu_fast(acc11[1])) << 16);
            p11 = f2bf(gelu_fast(acc11[2])) | (f2bf(gelu_fast(acc11[3])) << 16);
        }
        ushort_t* row = dst + (4 + n) * HSTR;
        *(uint2*)(row + quad * 4)      = make_uint2(p00, p01);
        *(uint2*)(row + 16 + quad * 4) = make_uint2(p10, p11);
    }
}

// 13 tiles over 4 waves: wave0 {0,4,8,12}, wave w {w, w+4, w+8}
template<int DIL>
__device__ __forceinline__ void conv_mfma(
    const ushort_t* __restrict__ src, ushort_t* __restrict__ dst,
    const ushort_t* __restrict__ wsf, const float* __restrict__ bias,
    int Lout, int lane, int wave)
{
    const int lo16 = lane & 15, quad = lane >> 4;
    short8 A[5][2];
    #pragma unroll
    for (int t = 0; t < 5; t++) {
        A[t][0] = *(const short8*)(wsf + (t * 2 + 0) * 512 + lane * 8);
        A[t][1] = *(const short8*)(wsf + (t * 2 + 1) * 512 + lane * 8);
    }
    f32x4 b0, b1;
    #pragma unroll
    for (int r = 0; r < 4; r++) { b0[r] = bias[quad * 4 + r]; b1[r] = bias[16 + quad * 4 + r]; }
    conv_tiles<DIL, true>(src, dst, A, b0, b1, Lout, lo16, quad, wave);
    if (wave == 0) conv_tiles<DIL, true>(src, dst, A, b0, b1, Lout, lo16, quad, 8);
    else           conv_tiles<DIL, false>(src, dst, A, b0, b1, Lout, lo16, quad, wave + 8);
}

__global__ void __launch_bounds__(NTHREADS, 4)
rminet_conv_kernel(const float* __restrict__ x,
                   const float* __restrict__ calib,
                   const float* __restrict__ biasv,
                   const float* __restrict__ cb1, const float* __restrict__ cb2,
                   const float* __restrict__ cb3, const float* __restrict__ cb4,
                   const ushort_t* __restrict__ wsp,
                   float* __restrict__ F)
{
    __shared__ __align__(16) ushort_t smh[SMEM_HW];
    const int tid  = threadIdx.x;
    const int b    = blockIdx.x;
    const int lane = tid & 63;
    const int wave = __builtin_amdgcn_readfirstlane(tid >> 6);

    // Zero bufA pad rows 0..3 (20 uint4) and ALL of bufB (1060 uint4).
    // LDS residue is arbitrary (can be bf16 NaN/Inf); MFMA 0*NaN = NaN, so
    // every byte an MFMA B-frag can touch must be initialized. (R4 bug:
    // only half of bufB was zeroed -> NaN.)
    {
        uint4* p = (uint4*)smh;
        for (int i = tid; i < 1080; i += NTHREADS) {
            int idx = (i < 20) ? i : (1060 + (i - 20));
            p[idx] = make_uint4(0u, 0u, 0u, 0u);
        }
    }
    __syncthreads();

    // calibrate + normalize -> bf16 xn rows [4+t][0..5] in bufB
    if (tid < 200) {
        const float* xc = x + (size_t)b * 1400 + 200 + tid;
        float v[6];
        #pragma unroll
        for (int ch = 0; ch < 6; ch++) v[ch] = xc[ch * 200];
        const float MEANS[6]  = {0.042766f, 0.0081577f, -0.015818f, 9.2993f, -0.087913f, -3.3231f};
        const float INVSTD[6] = {1.f/0.4142f, 1.f/0.3522f, 1.f/0.2881f, 1.f/1.474f, 1.f/0.6553f, 1.f/0.8728f};
        unsigned hv[6];
        #pragma unroll
        for (int i = 0; i < 6; i++) {
            float acc = biasv[i];
            #pragma unroll
            for (int jj = 0; jj < 6; jj++) {
                float m = calib[i * 6 + jj] + ((i == jj) ? 1.0f : 0.0f);
                acc = fmaf(m, v[jj], acc);
            }
            hv[i] = f2bf((acc - MEANS[i]) * INVSTD[i]);
        }
        ushort_t* row = smh + HB + (4 + tid) * HSTR;
        *(uint2*)row = make_uint2(hv[0] | (hv[1] << 16), hv[2] | (hv[3] << 16));
        *(unsigned*)(row + 4) = hv[4] | (hv[5] << 16);
    }
    __syncthreads();

    // conv1: xn(bufB) -> h1(bufA), dil=1, Lout=204
    conv_mfma<1>(smh + HB, smh + HA, wsp + WSF_C1, cb1, 204, lane, wave);
    __syncthreads();
    // conv2: h1(bufA) -> h2(bufB), dil=3, Lout=200
    conv_mfma<3>(smh + HA, smh + HB, wsp + WSF_C2, cb2, 200, lane, wave);
    __syncthreads();
    // conv3: h2(bufB) -> h3(bufA), dil=3, Lout=196
    conv_mfma<3>(smh + HB, smh + HA, wsp + WSF_C3, cb3, 196, lane, wave);
    __syncthreads();

    // conv4 (MFMA, M-row 0 only): h3 -> f[192], 12 tiles, 3 per wave
    {
        const int lo16 = lane & 15, quad = lane >> 4;
        short8 A4[5];
        #pragma unroll
        for (int t = 0; t < 5; t++)
            A4[t] = *(const short8*)(wsp + WSF_C4 + t * 512 + lane * 8);
        f32x4 acc[3];
        #pragma unroll
        for (int u = 0; u < 3; u++) acc[u] = (f32x4){0.f, 0.f, 0.f, 0.f};
        #pragma unroll
        for (int t = 0; t < 5; t++) {
            #pragma unroll
            for (int u = 0; u < 3; u++) {
                int r = (wave + 4 * u) * 16 + lo16 + 3 * t;   // <= 203
                short8 B = *(const short8*)(smh + HA + r * HSTR + quad * 8);
                acc[u] = __builtin_amdgcn_mfma_f32_16x16x32_bf16(A4[t], B, acc[u], 0, 0, 0);
            }
        }
        if (quad == 0) {
            const float c4 = cb4[0];
            #pragma unroll
            for (int u = 0; u < 3; u++) {
                int n = (wave + 4 * u) * 16 + lo16;
                F[(size_t)b * 192 + n] = gelu_fast(acc[u][0] + c4);
            }
        }
    }
}

// ---- kernel B: lane = item. linears fp32 (wave-uniform weights -> s_load),
// per-lane 3x3 SVD. F staged through LDS transposed (stride-65 float4 rows).
__global__ void __launch_bounds__(64)
rminet_tail_kernel(const float* __restrict__ F,
                   const float* __restrict__ lw1, const float* __restrict__ lb1,
                   const float* __restrict__ lw2, const float* __restrict__ lb2,
                   const float* __restrict__ lw3, const float* __restrict__ lb3,
                   float* __restrict__ out)
{
    __shared__ __align__(16) float4 FT[48 * 65];   // 49,920 B
    const int t  = threadIdx.x;
    const int i0 = blockIdx.x * 64;

    // coalesced load of 64 items' f vectors + transpose into LDS
    const float4* G4 = (const float4*)F + (size_t)i0 * 48;
    #pragma unroll 4
    for (int jj = 0; jj < 48; jj++) {
        int flat = jj * 64 + t;
        int it = flat / 48, k4 = flat - it * 48;
        FT[k4 * 65 + it] = G4[flat];
    }
    __syncthreads();

    // linear1: 192 -> 50 (2 passes x 25 accumulators), gelu exact
    float z1[50];
    #pragma unroll
    for (int p = 0; p < 2; p++) {
        float acc[25];
        #pragma unroll
        for (int c = 0; c < 25; c++) acc[c] = lb1[p * 25 + c];
        #pragma unroll 4
        for (int j = 0; j < 48; j++) {
            float4 f = FT[j * 65 + t];
            #pragma unroll
            for (int c = 0; c < 25; c++) {
                const float4 w = *(const float4*)&lw1[(p * 25 + c) * 192 + j * 4];
                acc[c] = fmaf(w.x, f.x, fmaf(w.y, f.y, fmaf(w.z, f.z, fmaf(w.w, f.w, acc[c]))));
            }
        }
        #pragma unroll
        for (int c = 0; c < 25; c++) z1[p * 25 + c] = gelu_exact(acc[c]);
    }

    // linear2: 50 -> 50 (z1 in regs, fully unrolled), gelu exact
    float z2[50];
    #pragma unroll
    for (int c = 0; c < 50; c++) {
        float a = lb2[c];
        #pragma unroll
        for (int k = 0; k < 50; k++) a = fmaf(lw2[c * 50 + k], z1[k], a);
        z2[c] = gelu_exact(a);
    }

    // linear3: 50 -> 15, *100
    float zv[15];
    #pragma unroll
    for (int c = 0; c < 15; c++) {
        float a = lb3[c];
        #pragma unroll
        for (int k = 0; k < 50; k++) a = fmaf(lw3[c * 50 + k], z2[k], a);
        zv[c] = a * 100.0f;
    }

    float* ob = out + (size_t)(i0 + t) * 15;
    #pragma unroll
    for (int c = 9; c < 15; c++) ob[c] = zv[c];

    // per-lane 3x3 SVD -> nearest rotation
    {
        const float A00 = zv[0], A01 = zv[1], A02 = zv[2];
        const float A10 = zv[3], A11 = zv[4], A12 = zv[5];
        const float A20 = zv[6], A21 = zv[7], A22 = zv[8];
        float S00 = A00*A00 + A10*A10 + A20*A20;
        float S01 = A00*A01 + A10*A11 + A20*A21;
        float S02 = A00*A02 + A10*A12 + A20*A22;
        float S11 = A01*A01 + A11*A11 + A21*A21;
        float S12 = A01*A02 + A11*A12 + A21*A22;
        float S22 = A02*A02 + A12*A12 + A22*A22;
        float V00=1.f, V01=0.f, V02=0.f;
        float V10=0.f, V11=1.f, V12=0.f;
        float V20=0.f, V21=0.f, V22=1.f;
        #pragma unroll
        for (int sweep = 0; sweep < 8; sweep++) {
            JROT(S00, S11, S01, S02, S12, V00, V01, V10, V11, V20, V21)
            JROT(S00, S22, S02, S01, S12, V00, V02, V10, V12, V20, V22)
            JROT(S11, S22, S12, S01, S02, V01, V02, V11, V12, V21, V22)
        }
        float e0 = S00, e1 = S11, e2 = S22;
        float va0=V00, va1=V10, va2=V20;
        float vb0=V01, vb1=V11, vb2=V21;
        float vc0=V02, vc1=V12, vc2=V22;
        float sgn = 1.0f, tq;
        if (e0 < e1) { tq=e0;e0=e1;e1=tq; tq=va0;va0=vb0;vb0=tq; tq=va1;va1=vb1;vb1=tq; tq=va2;va2=vb2;vb2=tq; sgn=-sgn; }
        if (e1 < e2) { tq=e1;e1=e2;e2=tq; tq=vb0;vb0=vc0;vc0=tq; tq=vb1;vb1=vc1;vc1=tq; tq=vb2;vb2=vc2;vc2=tq; sgn=-sgn; }
        if (e0 < e1) { tq=e0;e0=e1;e1=tq; tq=va0;va0=vb0;vb0=tq; tq=va1;va1=vb1;vb1=tq; tq=va2;va2=vb2;vb2=tq; sgn=-sgn; }
        vc0 *= sgn; vc1 *= sgn; vc2 *= sgn;
        float u10 = A00*va0 + A01*va1 + A02*va2;
        float u11 = A10*va0 + A11*va1 + A12*va2;
        float u12 = A20*va0 + A21*va1 + A22*va2;
        float n1 = sqrtf(u10*u10 + u11*u11 + u12*u12);
        float rn1 = (n1 > 1e-20f) ? 1.0f / n1 : 0.0f;
        u10 *= rn1; u11 *= rn1; u12 *= rn1;
        float u20 = A00*vb0 + A01*vb1 + A02*vb2;
        float u21 = A10*vb0 + A11*vb1 + A12*vb2;
        float u22 = A20*vb0 + A21*vb1 + A22*vb2;
        float d12 = u20*u10 + u21*u11 + u22*u12;
        u20 -= d12*u10; u21 -= d12*u11; u22 -= d12*u12;
        float n2 = sqrtf(u20*u20 + u21*u21 + u22*u22);
        float rn2 = (n2 > 1e-20f) ? 1.0f / n2 : 0.0f;
        u20 *= rn2; u21 *= rn2; u22 *= rn2;
        float u30 = u11*u22 - u12*u21;
        float u31 = u12*u20 - u10*u22;
        float u32 = u10*u21 - u11*u20;
        ob[0] = u10*va0 + u20*vb0 + u30*vc0;
        ob[1] = u10*va1 + u20*vb1 + u30*vc1;
        ob[2] = u10*va2 + u20*vb2 + u30*vc2;
        ob[3] = u11*va0 + u21*vb0 + u31*vc0;
        ob[4] = u11*va1 + u21*vb1 + u31*vc1;
        ob[5] = u11*va2 + u21*vb2 + u31*vc2;
        ob[6] = u12*va0 + u22*vb0 + u32*vc0;
        ob[7] = u12*va1 + u22*vb1 + u32*vc1;
        ob[8] = u12*va2 + u22*vb2 + u32*vc2;
    }
}

extern "C" void kernel_launch(void* const* d_in, const int* in_sizes, int n_in,
                              void* d_out, int out_size, void* d_ws, size_t ws_size,
                              hipStream_t stream) {
    (void)n_in; (void)out_size; (void)ws_size;
    const float* x     = (const float*)d_in[0];
    const float* calib = (const float*)d_in[1];
    const float* biasv = (const float*)d_in[2];
    const float* cw1   = (const float*)d_in[3];
    const float* cb1   = (const float*)d_in[4];
    const float* cw2   = (const float*)d_in[5];
    const float* cb2   = (const float*)d_in[6];
    const float* cw3   = (const float*)d_in[7];
    const float* cb3   = (const float*)d_in[8];
    const float* cw4   = (const float*)d_in[9];
    const float* cb4   = (const float*)d_in[10];
    const float* lw1   = (const float*)d_in[11];
    const float* lb1   = (const float*)d_in[12];
    const float* lw2   = (const float*)d_in[13];
    const float* lb2   = (const float*)d_in[14];
    const float* lw3   = (const float*)d_in[15];
    const float* lb3   = (const float*)d_in[16];
    float* out = (float*)d_out;
    ushort_t* wsh = (ushort_t*)d_ws;
    float* Fb = (float*)((char*)d_ws + WS_F_BYTE_OFF);
    const int B = in_sizes[0] / 1400;

    hipLaunchKernelGGL(prep_kernel, dim3(35), dim3(512), 0, stream,
                       cw1, cw2, cw3, cw4, wsh);
    hipLaunchKernelGGL(rminet_conv_kernel, dim3(B), dim3(NTHREADS), 0, stream,
                       x, calib, biasv, cb1, cb2, cb3, cb4,
                       (const ushort_t*)wsh, Fb);
    hipLaunchKernelGGL(rminet_tail_kernel, dim3(B / 64), dim3(64), 0, stream,
                       (const float*)Fb, lw1, lb1, lw2, lb2, lw3, lb3, out);
}

// Round 6
// 258.111 us; speedup vs baseline: 1.6692x; 1.6692x over previous
//
#include <hip/hip_runtime.h>
#include <math.h>

#define NTHREADS 256
typedef __attribute__((ext_vector_type(8))) short short8;
typedef __attribute__((ext_vector_type(4))) float f32x4;
typedef unsigned short ushort_t;

// ---- Kernel A LDS: two time-major activation buffers hT[row=t+4][ch],
// 212 rows x stride 40 bf16 (80 B, 16B-aligned rows). B-frag = 8 contiguous
// channels at one row = one ds_read_b128. 33,920 B -> 4 blocks/CU.
#define HA    0          // bufA: h1, then h3
#define HB    8480       // bufB: xn (ch 0..5, rest zero), then h2
#define HSTR  40
#define SMEM_HW 16960

// ws layout: 35 A-frags bf16 (512 hw each) at 0; F fp32 at byte 65536.
#define WSF_C1 0
#define WSF_C2 (10*512)
#define WSF_C3 (20*512)
#define WSF_C4 (30*512)
#define WS_F_BYTE_OFF 65536

__device__ __forceinline__ unsigned f2bf(float f) {
    unsigned u = __float_as_uint(f);
    return (u + 0x7FFFu + ((u >> 16) & 1u)) >> 16;
}

__device__ __forceinline__ float gelu_fast(float x) {
    float x2 = x * x;
    float u  = x * fmaf(0.044715f, x2, 1.0f);
    float e  = __builtin_amdgcn_exp2f(u * 2.3022082f);
    float r  = __builtin_amdgcn_rcpf(e + 1.0f);
    float th = fmaf(-2.0f, r, 1.0f);
    float hx = 0.5f * x;
    return fmaf(hx, th, hx);
}

__device__ __forceinline__ float gelu_exact(float v) {
    return 0.5f * v * (1.0f + erff(v * 0.70710678118654752f));
}

#define JROT(Spp, Sqq, Spq, Sxp, Sxq, Vp0, Vq0, Vp1, Vq1, Vp2, Vq2)          \
    if (fabsf(Spq) > 1e-18f) {                                               \
        float tau = (Sqq - Spp) / (2.0f * Spq);                              \
        float tj = copysignf(1.0f, tau) / (fabsf(tau) + sqrtf(1.0f + tau*tau)); \
        float cj = 1.0f / sqrtf(1.0f + tj*tj);                               \
        float sj = tj * cj;                                                  \
        Spp -= tj * Spq; Sqq += tj * Spq; Spq = 0.0f;                        \
        float tmp0 = Sxp; Sxp = cj*tmp0 - sj*Sxq; Sxq = sj*tmp0 + cj*Sxq;    \
        float tv;                                                            \
        tv = Vp0; Vp0 = cj*tv - sj*Vq0; Vq0 = sj*tv + cj*Vq0;                \
        tv = Vp1; Vp1 = cj*tv - sj*Vq1; Vq1 = sj*tv + cj*Vq1;                \
        tv = Vp2; Vp2 = cj*tv - sj*Vq2; Vq2 = sj*tv + cj*Vq2;                \
    }

// ---- prep: repack conv weights into MFMA A-frag lane order (bf16).
__global__ void prep_kernel(const float* __restrict__ cw1,
                            const float* __restrict__ cw2,
                            const float* __restrict__ cw3,
                            const float* __restrict__ cw4,
                            ushort_t* __restrict__ ws)
{
    const int fid = blockIdx.x;              // 0..34
    const int l = threadIdx.x >> 3, j = threadIdx.x & 7;
    const int lo = l & 15, q = l >> 4;
    const int k = q * 8 + j;                 // 0..31
    float v = 0.0f;
    if (fid < 10) {                          // conv1: K=32, only i<6 real
        int tap = fid >> 1, Mt = fid & 1, c = Mt * 16 + lo;
        if (k < 6) v = cw1[(c * 6 + k) * 5 + tap];
    } else if (fid < 20) {                   // conv2
        int f = fid - 10, tap = f >> 1, Mt = f & 1, c = Mt * 16 + lo;
        v = cw2[(c * 32 + k) * 5 + tap];
    } else if (fid < 30) {                   // conv3
        int f = fid - 20, tap = f >> 1, Mt = f & 1, c = Mt * 16 + lo;
        v = cw3[(c * 32 + k) * 5 + tap];
    } else {                                 // conv4: row 0 only
        int tap = fid - 30;
        if (lo == 0) v = cw4[k * 5 + tap];
    }
    ws[fid * 512 + l * 8 + j] = (ushort_t)f2bf(v);
}

// ---- process 1 or 2 conv tiles (tile t0 and t0+4) interleaved for ILP ----
template<int DIL, bool TWO>
__device__ __forceinline__ void conv_tiles(
    const ushort_t* __restrict__ src, ushort_t* __restrict__ dst,
    const short8 A[5][2], f32x4 b0, f32x4 b1, int Lout,
    int lo16, int quad, int t0)
{
    f32x4 acc00 = b0, acc01 = b1, acc10 = b0, acc11 = b1;
    const int n0a = t0 * 16, n0b = (t0 + 4) * 16;
    #pragma unroll
    for (int t = 0; t < 5; t++) {
        int ra = n0a + lo16 + DIL * t; if (DIL == 3) ra = min(ra, 211);
        short8 Ba = *(const short8*)(src + ra * HSTR + quad * 8);
        acc00 = __builtin_amdgcn_mfma_f32_16x16x32_bf16(A[t][0], Ba, acc00, 0, 0, 0);
        acc01 = __builtin_amdgcn_mfma_f32_16x16x32_bf16(A[t][1], Ba, acc01, 0, 0, 0);
        if (TWO) {
            int rb = n0b + lo16 + DIL * t; if (DIL == 3) rb = min(rb, 211);
            short8 Bb = *(const short8*)(src + rb * HSTR + quad * 8);
            acc10 = __builtin_amdgcn_mfma_f32_16x16x32_bf16(A[t][0], Bb, acc10, 0, 0, 0);
            acc11 = __builtin_amdgcn_mfma_f32_16x16x32_bf16(A[t][1], Bb, acc11, 0, 0, 0);
        }
    }
    {
        const int n = n0a + lo16;
        unsigned p00 = 0, p01 = 0, p10 = 0, p11 = 0;
        if (n < Lout) {
            p00 = f2bf(gelu_fast(acc00[0])) | (f2bf(gelu_fast(acc00[1])) << 16);
            p01 = f2bf(gelu_fast(acc00[2])) | (f2bf(gelu_fast(acc00[3])) << 16);
            p10 = f2bf(gelu_fast(acc01[0])) | (f2bf(gelu_fast(acc01[1])) << 16);
            p11 = f2bf(gelu_fast(acc01[2])) | (f2bf(gelu_fast(acc01[3])) << 16);
        }
        ushort_t* row = dst + (4 + n) * HSTR;
        *(uint2*)(row + quad * 4)      = make_uint2(p00, p01);
        *(uint2*)(row + 16 + quad * 4) = make_uint2(p10, p11);
    }
    if (TWO) {
        const int n = n0b + lo16;
        unsigned p00 = 0, p01 = 0, p10 = 0, p11 = 0;
        if (n < Lout) {
            p00 = f2bf(gelu_fast(acc10[0])) | (f2bf(gelu_fast(acc10[1])) << 16);
            p01 = f2bf(gelu_fast(acc10[2])) | (f2bf(gelu_fast(acc10[3])) << 16);
            p10 = f2bf(gelu_fast(acc11[0])) | (f2bf(gelu_fast(acc11[1])) << 16);
            p11 = f2bf(gelu_fast(acc11[2])) | (f2bf(gelu_fast(acc11[3])) << 16);
        }
        ushort_t* row = dst + (4 + n) * HSTR;
        *(uint2*)(row + quad * 4)      = make_uint2(p00, p01);
        *(uint2*)(row + 16 + quad * 4) = make_uint2(p10, p11);
    }
}

// 13 tiles over 4 waves: wave0 {0,4,8,12}, wave w {w, w+4, w+8}
template<int DIL>
__device__ __forceinline__ void conv_mfma(
    const ushort_t* __restrict__ src, ushort_t* __restrict__ dst,
    const ushort_t* __restrict__ wsf, const float* __restrict__ bias,
    int Lout, int lane, int wave)
{
    const int lo16 = lane & 15, quad = lane >> 4;
    short8 A[5][2];
    #pragma unroll
    for (int t = 0; t < 5; t++) {
        A[t][0] = *(const short8*)(wsf + (t * 2 + 0) * 512 + lane * 8);
        A[t][1] = *(const short8*)(wsf + (t * 2 + 1) * 512 + lane * 8);
    }
    f32x4 b0, b1;
    #pragma unroll
    for (int r = 0; r < 4; r++) { b0[r] = bias[quad * 4 + r]; b1[r] = bias[16 + quad * 4 + r]; }
    conv_tiles<DIL, true>(src, dst, A, b0, b1, Lout, lo16, quad, wave);
    if (wave == 0) conv_tiles<DIL, true>(src, dst, A, b0, b1, Lout, lo16, quad, 8);
    else           conv_tiles<DIL, false>(src, dst, A, b0, b1, Lout, lo16, quad, wave + 8);
}

__global__ void __launch_bounds__(NTHREADS, 4)
rminet_conv_kernel(const float* __restrict__ x,
                   const float* __restrict__ calib,
                   const float* __restrict__ biasv,
                   const float* __restrict__ cb1, const float* __restrict__ cb2,
                   const float* __restrict__ cb3, const float* __restrict__ cb4,
                   const ushort_t* __restrict__ wsp,
                   float* __restrict__ F)
{
    __shared__ __align__(16) ushort_t smh[SMEM_HW];
    const int tid  = threadIdx.x;
    const int b    = blockIdx.x;
    const int lane = tid & 63;
    const int wave = __builtin_amdgcn_readfirstlane(tid >> 6);

    // Zero bufA pad rows 0..3 (20 uint4) and ALL of bufB (1060 uint4).
    // LDS residue can be bf16 NaN/Inf; MFMA 0*NaN = NaN.
    {
        uint4* p = (uint4*)smh;
        for (int i = tid; i < 1080; i += NTHREADS) {
            int idx = (i < 20) ? i : (1060 + (i - 20));
            p[idx] = make_uint4(0u, 0u, 0u, 0u);
        }
    }
    __syncthreads();

    // calibrate + normalize -> bf16 xn rows [4+t][0..5] in bufB
    if (tid < 200) {
        const float* xc = x + (size_t)b * 1400 + 200 + tid;
        float v[6];
        #pragma unroll
        for (int ch = 0; ch < 6; ch++) v[ch] = xc[ch * 200];
        const float MEANS[6]  = {0.042766f, 0.0081577f, -0.015818f, 9.2993f, -0.087913f, -3.3231f};
        const float INVSTD[6] = {1.f/0.4142f, 1.f/0.3522f, 1.f/0.2881f, 1.f/1.474f, 1.f/0.6553f, 1.f/0.8728f};
        unsigned hv[6];
        #pragma unroll
        for (int i = 0; i < 6; i++) {
            float acc = biasv[i];
            #pragma unroll
            for (int jj = 0; jj < 6; jj++) {
                float m = calib[i * 6 + jj] + ((i == jj) ? 1.0f : 0.0f);
                acc = fmaf(m, v[jj], acc);
            }
            hv[i] = f2bf((acc - MEANS[i]) * INVSTD[i]);
        }
        ushort_t* row = smh + HB + (4 + tid) * HSTR;
        *(uint2*)row = make_uint2(hv[0] | (hv[1] << 16), hv[2] | (hv[3] << 16));
        *(unsigned*)(row + 4) = hv[4] | (hv[5] << 16);
    }
    __syncthreads();

    // conv1: xn(bufB) -> h1(bufA), dil=1, Lout=204
    conv_mfma<1>(smh + HB, smh + HA, wsp + WSF_C1, cb1, 204, lane, wave);
    __syncthreads();
    // conv2: h1(bufA) -> h2(bufB), dil=3, Lout=200
    conv_mfma<3>(smh + HA, smh + HB, wsp + WSF_C2, cb2, 200, lane, wave);
    __syncthreads();
    // conv3: h2(bufB) -> h3(bufA), dil=3, Lout=196
    conv_mfma<3>(smh + HB, smh + HA, wsp + WSF_C3, cb3, 196, lane, wave);
    __syncthreads();

    // conv4 (MFMA, M-row 0 only): h3 -> f[192], 12 tiles, 3 per wave
    {
        const int lo16 = lane & 15, quad = lane >> 4;
        short8 A4[5];
        #pragma unroll
        for (int t = 0; t < 5; t++)
            A4[t] = *(const short8*)(wsp + WSF_C4 + t * 512 + lane * 8);
        f32x4 acc[3];
        #pragma unroll
        for (int u = 0; u < 3; u++) acc[u] = (f32x4){0.f, 0.f, 0.f, 0.f};
        #pragma unroll
        for (int t = 0; t < 5; t++) {
            #pragma unroll
            for (int u = 0; u < 3; u++) {
                int r = (wave + 4 * u) * 16 + lo16 + 3 * t;   // <= 203
                short8 B = *(const short8*)(smh + HA + r * HSTR + quad * 8);
                acc[u] = __builtin_amdgcn_mfma_f32_16x16x32_bf16(A4[t], B, acc[u], 0, 0, 0);
            }
        }
        if (quad == 0) {
            const float c4 = cb4[0];
            #pragma unroll
            for (int u = 0; u < 3; u++) {
                int n = (wave + 4 * u) * 16 + lo16;
                F[(size_t)b * 192 + n] = gelu_fast(acc[u][0] + c4);
            }
        }
    }
}

// ---- kernel B: 256 threads / 64 items. lane = item, wave g = output-channel
// slice (c = 4k+g, wave-uniform -> weights via s_load). 4 waves/CU.
// LDS (floats): FT region [0,12480) = 48x65 float4 transposed f (conflict-free,
// proven 0-conflict in R5); reused for z2 (stride 52) after linear1.
// Z1 region [12480,15808) = 64x52 z1; reused for zv (stride 20) after linear2.
#define TF_Z1 12480
#define TSM_FLOATS 15808   // 63,232 B

__global__ void __launch_bounds__(256)
rminet_tail_kernel(const float* __restrict__ F,
                   const float* __restrict__ lw1, const float* __restrict__ lb1,
                   const float* __restrict__ lw2, const float* __restrict__ lb2,
                   const float* __restrict__ lw3, const float* __restrict__ lb3,
                   float* __restrict__ out)
{
    __shared__ __align__(16) float smt[TSM_FLOATS];
    const int tid  = threadIdx.x;
    const int lane = tid & 63;                                  // item within block
    const int g    = __builtin_amdgcn_readfirstlane(tid >> 6);  // wave slice 0..3
    const int i0   = blockIdx.x * 64;

    // coalesced load of 64 items' f vectors -> transposed FT[k4*65 + item]
    {
        const float4* G4 = (const float4*)F + (size_t)i0 * 48;
        float4* FT = (float4*)smt;
        #pragma unroll
        for (int r = 0; r < 12; r++) {
            int flat = r * 256 + tid;               // 0..3071
            int it = flat / 48, k4 = flat - it * 48;
            FT[k4 * 65 + it] = G4[flat];
        }
    }
    __syncthreads();

    // ---- linear1: 192 -> 50, c = 4k+g (13 accs), gelu exact -> z1 LDS ----
    {
        float acc[13];
        #pragma unroll
        for (int k = 0; k < 13; k++) {
            int c = min(4 * k + g, 49);
            acc[k] = lb1[c];
        }
        for (int j = 0; j < 48; j++) {
            float4 f = *(const float4*)&smt[(j * 65 + lane) * 4];
            #pragma unroll
            for (int k = 0; k < 13; k++) {
                int c = min(4 * k + g, 49);          // clamp: garbage discarded
                const float4 w = *(const float4*)&lw1[c * 192 + 4 * j];
                acc[k] = fmaf(w.x, f.x, fmaf(w.y, f.y, fmaf(w.z, f.z, fmaf(w.w, f.w, acc[k]))));
            }
        }
        #pragma unroll
        for (int k = 0; k < 13; k++) {
            int c = 4 * k + g;
            if (c < 50) smt[TF_Z1 + lane * 52 + c] = gelu_exact(acc[k]);
        }
    }
    __syncthreads();

    // ---- linear2: 50 -> 50, c = 4k+g, gelu exact -> z2 (FT region, stride 52) ----
    {
        float acc[13];
        #pragma unroll
        for (int k = 0; k < 13; k++) {
            int c = min(4 * k + g, 49);
            acc[k] = lb2[c];
        }
        for (int j = 0; j < 25; j++) {               // float2 chunks (8B-aligned)
            float2 z = *(const float2*)&smt[TF_Z1 + lane * 52 + 2 * j];
            #pragma unroll
            for (int k = 0; k < 13; k++) {
                int c = min(4 * k + g, 49);
                const float2 w = *(const float2*)&lw2[c * 50 + 2 * j];
                acc[k] = fmaf(w.x, z.x, fmaf(w.y, z.y, acc[k]));
            }
        }
        #pragma unroll
        for (int k = 0; k < 13; k++) {
            int c = 4 * k + g;
            if (c < 50) smt[lane * 52 + c] = gelu_exact(acc[k]);
        }
    }
    __syncthreads();

    // ---- linear3: 50 -> 15, c = 4k+g (k<4), *100 -> zv (Z1 region, stride 20) ----
    {
        float acc[4];
        #pragma unroll
        for (int k = 0; k < 4; k++) {
            int c = min(4 * k + g, 14);
            acc[k] = lb3[c];
        }
        for (int j = 0; j < 25; j++) {
            float2 z = *(const float2*)&smt[lane * 52 + 2 * j];
            #pragma unroll
            for (int k = 0; k < 4; k++) {
                int c = min(4 * k + g, 14);
                const float2 w = *(const float2*)&lw3[c * 50 + 2 * j];
                acc[k] = fmaf(w.x, z.x, fmaf(w.y, z.y, acc[k]));
            }
        }
        #pragma unroll
        for (int k = 0; k < 4; k++) {
            int c = 4 * k + g;
            if (c < 15) smt[TF_Z1 + lane * 20 + c] = acc[k] * 100.0f;
        }
    }
    __syncthreads();

    // ---- wave 0: per-lane 3x3 SVD -> nearest rotation + tail outputs ----
    if (g == 0) {
        float zv[15];
        #pragma unroll
        for (int c = 0; c < 15; c++) zv[c] = smt[TF_Z1 + lane * 20 + c];
        float* ob = out + (size_t)(i0 + lane) * 15;
        #pragma unroll
        for (int c = 9; c < 15; c++) ob[c] = zv[c];

        const float A00 = zv[0], A01 = zv[1], A02 = zv[2];
        const float A10 = zv[3], A11 = zv[4], A12 = zv[5];
        const float A20 = zv[6], A21 = zv[7], A22 = zv[8];
        float S00 = A00*A00 + A10*A10 + A20*A20;
        float S01 = A00*A01 + A10*A11 + A20*A21;
        float S02 = A00*A02 + A10*A12 + A20*A22;
        float S11 = A01*A01 + A11*A11 + A21*A21;
        float S12 = A01*A02 + A11*A12 + A21*A22;
        float S22 = A02*A02 + A12*A12 + A22*A22;
        float V00=1.f, V01=0.f, V02=0.f;
        float V10=0.f, V11=1.f, V12=0.f;
        float V20=0.f, V21=0.f, V22=1.f;
        #pragma unroll
        for (int sweep = 0; sweep < 8; sweep++) {
            JROT(S00, S11, S01, S02, S12, V00, V01, V10, V11, V20, V21)
            JROT(S00, S22, S02, S01, S12, V00, V02, V10, V12, V20, V22)
            JROT(S11, S22, S12, S01, S02, V01, V02, V11, V12, V21, V22)
        }
        float e0 = S00, e1 = S11, e2 = S22;
        float va0=V00, va1=V10, va2=V20;
        float vb0=V01, vb1=V11, vb2=V21;
        float vc0=V02, vc1=V12, vc2=V22;
        float sgn = 1.0f, tq;
        if (e0 < e1) { tq=e0;e0=e1;e1=tq; tq=va0;va0=vb0;vb0=tq; tq=va1;va1=vb1;vb1=tq; tq=va2;va2=vb2;vb2=tq; sgn=-sgn; }
        if (e1 < e2) { tq=e1;e1=e2;e2=tq; tq=vb0;vb0=vc0;vc0=tq; tq=vb1;vb1=vc1;vc1=tq; tq=vb2;vb2=vc2;vc2=tq; sgn=-sgn; }
        if (e0 < e1) { tq=e0;e0=e1;e1=tq; tq=va0;va0=vb0;vb0=tq; tq=va1;va1=vb1;vb1=tq; tq=va2;va2=vb2;vb2=tq; sgn=-sgn; }
        vc0 *= sgn; vc1 *= sgn; vc2 *= sgn;
        float u10 = A00*va0 + A01*va1 + A02*va2;
        float u11 = A10*va0 + A11*va1 + A12*va2;
        float u12 = A20*va0 + A21*va1 + A22*va2;
        float n1 = sqrtf(u10*u10 + u11*u11 + u12*u12);
        float rn1 = (n1 > 1e-20f) ? 1.0f / n1 : 0.0f;
        u10 *= rn1; u11 *= rn1; u12 *= rn1;
        float u20 = A00*vb0 + A01*vb1 + A02*vb2;
        float u21 = A10*vb0 + A11*vb1 + A12*vb2;
        float u22 = A20*vb0 + A21*vb1 + A22*vb2;
        float d12 = u20*u10 + u21*u11 + u22*u12;
        u20 -= d12*u10; u21 -= d12*u11; u22 -= d12*u12;
        float n2 = sqrtf(u20*u20 + u21*u21 + u22*u22);
        float rn2 = (n2 > 1e-20f) ? 1.0f / n2 : 0.0f;
        u20 *= rn2; u21 *= rn2; u22 *= rn2;
        float u30 = u11*u22 - u12*u21;
        float u31 = u12*u20 - u10*u22;
        float u32 = u10*u21 - u11*u20;
        ob[0] = u10*va0 + u20*vb0 + u30*vc0;
        ob[1] = u10*va1 + u20*vb1 + u30*vc1;
        ob[2] = u10*va2 + u20*vb2 + u30*vc2;
        ob[3] = u11*va0 + u21*vb0 + u31*vc0;
        ob[4] = u11*va1 + u21*vb1 + u31*vc1;
        ob[5] = u11*va2 + u21*vb2 + u31*vc2;
        ob[6] = u12*va0 + u22*vb0 + u32*vc0;
        ob[7] = u12*va1 + u22*vb1 + u32*vc1;
        ob[8] = u12*va2 + u22*vb2 + u32*vc2;
    }
}

extern "C" void kernel_launch(void* const* d_in, const int* in_sizes, int n_in,
                              void* d_out, int out_size, void* d_ws, size_t ws_size,
                              hipStream_t stream) {
    (void)n_in; (void)out_size; (void)ws_size;
    const float* x     = (const float*)d_in[0];
    const float* calib = (const float*)d_in[1];
    const float* biasv = (const float*)d_in[2];
    const float* cw1   = (const float*)d_in[3];
    const float* cb1   = (const float*)d_in[4];
    const float* cw2   = (const float*)d_in[5];
    const float* cb2   = (const float*)d_in[6];
    const float* cw3   = (const float*)d_in[7];
    const float* cb3   = (const float*)d_in[8];
    const float* cw4   = (const float*)d_in[9];
    const float* cb4   = (const float*)d_in[10];
    const float* lw1   = (const float*)d_in[11];
    const float* lb1   = (const float*)d_in[12];
    const float* lw2   = (const float*)d_in[13];
    const float* lb2   = (const float*)d_in[14];
    const float* lw3   = (const float*)d_in[15];
    const float* lb3   = (const float*)d_in[16];
    float* out = (float*)d_out;
    ushort_t* wsh = (ushort_t*)d_ws;
    float* Fb = (float*)((char*)d_ws + WS_F_BYTE_OFF);
    const int B = in_sizes[0] / 1400;

    hipLaunchKernelGGL(prep_kernel, dim3(35), dim3(512), 0, stream,
                       cw1, cw2, cw3, cw4, wsh);
    hipLaunchKernelGGL(rminet_conv_kernel, dim3(B), dim3(NTHREADS), 0, stream,
                       x, calib, biasv, cb1, cb2, cb3, cb4,
                       (const ushort_t*)wsh, Fb);
    hipLaunchKernelGGL(rminet_tail_kernel, dim3(B / 64), dim3(256), 0, stream,
                       (const float*)Fb, lw1, lb1, lw2, lb2, lw3, lb3, out);
}